// Round 11
// baseline (3095.718 us; speedup 1.0000x reference)
//
#include <hip/hip_runtime.h>
#include <cstdint>
#include <cstddef>

typedef unsigned short u16;
typedef unsigned int u32;
typedef unsigned long long u64;
typedef __attribute__((ext_vector_type(8))) short bf16x8;  // 8 x bf16 (4 VGPRs)
typedef __attribute__((ext_vector_type(4))) float f32x4;

#define DEV __device__ __forceinline__

DEV float bf2f(u16 h) { union { u32 u; float f; } x; x.u = ((u32)h) << 16; return x.f; }
DEV u16 f2bf(float f) {
    union { float f; u32 u; } x; x.f = f;
    u32 u = x.u;
    return (u16)((u + 0x7fffu + ((u >> 16) & 1u)) >> 16);   // RNE
}
// fast gate math: __expf + v_rcp_f32; rel err ~1e-6 << bf16 weight rounding
DEV float fsig(float x)  { float e = __expf(-x);      return __builtin_amdgcn_rcpf(1.0f + e); }
DEV float ftanh(float x) { float e = __expf(2.0f * x); return 1.0f - 2.0f * __builtin_amdgcn_rcpf(e + 1.0f); }
DEV f32x4 mfma16(bf16x8 a, bf16x8 b, f32x4 c) {
    return __builtin_amdgcn_mfma_f32_16x16x32_bf16(a, b, c, 0, 0, 0);
}

// B=256, T=256, E=128, H=128 (per direction), H2=256. ALL tensors fp32.
// CH=32 time chunks, double-buffered xg (2x32 MiB). Fused dispatches use a
// TOTAL grid of 256 wgs (= #CUs): recur wgs first (co-resident, dedicated
// CUs), persistent GEMM wgs loop over tiles on the remaining CUs — r10's
// 2176-wg fusion packed ~8 wgs/CU and stretched the recur critical path
// 2.46 -> 4.4 us/step via intra-CU issue contention.
#define CH 32

// ---------------------------------------------------------------------------
// GEMM bodies (shared LDS pool, 10240 B: As 5120 + Bs 5120)
// ---------------------------------------------------------------------------
DEV void xg_fr_body(char* lds, int bx, int by, int halfY,
    const float* __restrict__ embed,
    const float* __restrict__ Wf, const float* __restrict__ bf_,
    const float* __restrict__ Wr, const float* __restrict__ br_,
    float* __restrict__ xgf, float* __restrict__ xgr, int t0f, int t0r)
{
    u16 (*As)[40] = (u16(*)[40])lds;
    u16 (*Bs)[40] = (u16(*)[40])(lds + 5120);
    int tid = threadIdx.x;
    bool isR = by >= halfY;
    int m0 = (by - (isR ? halfY : 0)) * 64;
    const float* W    = isR ? Wr  : Wf;
    const float* bias = isR ? br_ : bf_;
    float* out        = isR ? xgr : xgf;
    int tbase         = isR ? t0r : t0f;
    int n0 = bx * 64;

    int r  = tid >> 2;
    int kc = (tid & 3) * 8;
    int m  = m0 + r;
    int tl = m >> 8, bb = m & 255;
    const float* arow = embed + ((size_t)(bb * 256 + (tbase + tl)) * 128);
    const float* brow = W + ((size_t)(n0 + r) * 128);

    f32x4 acc[4];
    #pragma unroll
    for (int i = 0; i < 4; ++i) acc[i] = (f32x4){0.f, 0.f, 0.f, 0.f};
    int lane = tid & 63, w = tid >> 6;
    int fr_ = lane & 15, kb0 = (lane >> 4) * 8;

    for (int kt = 0; kt < 8; ++kt) {
        int sc = (kt & 3) * 32 + kc;
        bool lo = kt >= 4;
        f32x4 va = *(const f32x4*)(arow + sc);
        f32x4 vb = *(const f32x4*)(arow + sc + 4);
        f32x4 wa = *(const f32x4*)(brow + sc);
        f32x4 wb = *(const f32x4*)(brow + sc + 4);
        bf16x8 hv, wv;
        #pragma unroll
        for (int i = 0; i < 8; ++i) {
            float v = (i < 4) ? va[i] : vb[i - 4];
            u16 hi = f2bf(v);
            hv[i] = (short)(lo ? f2bf(v - bf2f(hi)) : hi);
            float wf = (i < 4) ? wa[i] : wb[i - 4];
            wv[i] = (short)f2bf(wf);
        }
        *(bf16x8*)&As[r][kc] = hv;
        *(bf16x8*)&Bs[r][kc] = wv;
        __syncthreads();
        bf16x8 bfrg = *(const bf16x8*)&Bs[w * 16 + fr_][kb0];
        #pragma unroll
        for (int mt = 0; mt < 4; ++mt) {
            bf16x8 afrg = *(const bf16x8*)&As[mt * 16 + fr_][kb0];
            acc[mt] = mfma16(afrg, bfrg, acc[mt]);
        }
        __syncthreads();
    }
    int col = n0 + w * 16 + fr_;
    float bvv = bias[col];
    int rq = (lane >> 4) * 4;
    #pragma unroll
    for (int mt = 0; mt < 4; ++mt)
        #pragma unroll
        for (int rr = 0; rr < 4; ++rr) {
            int mrow = m0 + mt * 16 + rq + rr;
            out[(size_t)mrow * 512 + col] = acc[mt][rr] + bvv;
        }
}

DEV void xg_l_body(char* lds, int bx, int by,
    const float* __restrict__ X, const float* __restrict__ W,
    const float* __restrict__ bias, float* __restrict__ out, int t0)
{
    u16 (*As)[40] = (u16(*)[40])lds;
    u16 (*Bs)[40] = (u16(*)[40])(lds + 5120);
    int tid = threadIdx.x;
    int m0 = by * 64, n0 = bx * 64;
    int r  = tid >> 2;
    int kc = (tid & 3) * 8;
    int m  = m0 + r;
    int tl = m >> 8, bb = m & 255;
    const float* arow = X + ((size_t)((t0 + tl) * 256 + bb) * 256);
    const float* brow = W + ((size_t)(n0 + r) * 256);

    f32x4 acc[4];
    #pragma unroll
    for (int i = 0; i < 4; ++i) acc[i] = (f32x4){0.f, 0.f, 0.f, 0.f};
    int lane = tid & 63, w = tid >> 6;
    int fr_ = lane & 15, kb0 = (lane >> 4) * 8;

    for (int kt = 0; kt < 16; ++kt) {
        int sc = (kt & 7) * 32 + kc;
        bool lo = kt >= 8;
        f32x4 va = *(const f32x4*)(arow + sc);
        f32x4 vb = *(const f32x4*)(arow + sc + 4);
        f32x4 wa = *(const f32x4*)(brow + sc);
        f32x4 wb = *(const f32x4*)(brow + sc + 4);
        bf16x8 hv, wv;
        #pragma unroll
        for (int i = 0; i < 8; ++i) {
            float v = (i < 4) ? va[i] : vb[i - 4];
            u16 hi = f2bf(v);
            hv[i] = (short)(lo ? f2bf(v - bf2f(hi)) : hi);
            float wf = (i < 4) ? wa[i] : wb[i - 4];
            wv[i] = (short)f2bf(wf);
        }
        *(bf16x8*)&As[r][kc] = hv;
        *(bf16x8*)&Bs[r][kc] = wv;
        __syncthreads();
        bf16x8 bfrg = *(const bf16x8*)&Bs[w * 16 + fr_][kb0];
        #pragma unroll
        for (int mt = 0; mt < 4; ++mt) {
            bf16x8 afrg = *(const bf16x8*)&As[mt * 16 + fr_][kb0];
            acc[mt] = mfma16(afrg, bfrg, acc[mt]);
        }
        __syncthreads();
    }
    int col = n0 + w * 16 + fr_;
    float bvv = bias[col];
    int rq = (lane >> 4) * 4;
    #pragma unroll
    for (int mt = 0; mt < 4; ++mt)
        #pragma unroll
        for (int rr = 0; rr < 4; ++rr) {
            int mrow = m0 + mt * 16 + rq + rr;
            out[(size_t)mrow * 1024 + col] = acc[mt][rr] + bvv;
        }
}

// ---------------------------------------------------------------------------
// Recurrence bodies (r9-verified math, LDS via pool)
// ---------------------------------------------------------------------------
DEV void recur1_body(char* lds, int bid,
    const float* __restrict__ xgf, const float* __restrict__ xgr,
    const float* __restrict__ whhf, const float* __restrict__ whhr,
    float* __restrict__ cbf, float* __restrict__ cbr,
    float* __restrict__ hpf, float* __restrict__ hpr,
    float* __restrict__ xout, int s0, int s1)
{
    constexpr int K = 128, N4 = 512;
    typedef u16 Al1Buf[16][136];
    Al1Buf* Al = (Al1Buf*)lds;   // [2][16][136] = 8704 B

    int tid = threadIdx.x, lane = tid & 63, w = tid >> 6;
    int fr_ = lane & 15, quad = lane >> 4, kb0 = quad * 8;
    int dir = bid >> 5, gidx = bid & 31;
    const float* xg  = dir ? xgr  : xgf;
    const float* whh = dir ? whhr : whhf;
    float* cb = dir ? cbr : cbf;
    float* hp = dir ? hpr : hpf;
    int coloff = dir ? 128 : 0;

    bf16x8 bf[4][2][4];
    #pragma unroll
    for (int g = 0; g < 4; ++g)
        #pragma unroll
        for (int u = 0; u < 2; ++u) {
            const float* src = whh + (size_t)(g * K + w * 32 + u * 16 + fr_) * K;
            #pragma unroll
            for (int kt = 0; kt < 4; ++kt) {
                f32x4 a = *(const f32x4*)(src + kt * 32 + kb0);
                f32x4 b = *(const f32x4*)(src + kt * 32 + kb0 + 4);
                bf16x8 wv;
                #pragma unroll
                for (int i = 0; i < 8; ++i) wv[i] = (short)f2bf((i < 4) ? a[i] : b[i - 4]);
                bf[g][u][kt] = wv;
            }
        }

    int uq = quad >> 1, qrow = quad & 1;
    int colw = w * 32 + uq * 16 + fr_;        // 0..127
    int b0 = gidx * 8;
    float c[4];
    #pragma unroll
    for (int rr = 0; rr < 4; ++rr)
        c[rr] = (s0 > 0) ? cb[(size_t)(b0 + qrow * 4 + rr) * K + colw] : 0.f;

    if (s0 > 0) {
        for (int idx = tid; idx < 8 * K; idx += 256) {
            int sa = idx >> 7, k = idx & 127;
            float v = hp[(size_t)(b0 + sa) * K + k];
            u16 hh = f2bf(v);
            Al[s0 & 1][sa][k] = hh;
            Al[s0 & 1][8 + sa][k] = f2bf(v - bf2f(hh));
        }
    }
    __syncthreads();

    for (int t = s0; t < s1; ++t) {
        int xrow = dir ? (s1 - 1 - t) : (t - s0);
        float xv[4][4];
        #pragma unroll
        for (int rr = 0; rr < 4; ++rr) {
            const float* xp = xg + ((size_t)(xrow * 256 + b0 + qrow * 4 + rr)) * N4 + colw;
            #pragma unroll
            for (int g = 0; g < 4; ++g) xv[rr][g] = xp[g * K];
        }
        f32x4 acc[4][2];
        if (t > 0) {
            #pragma unroll
            for (int g = 0; g < 4; ++g)
                #pragma unroll
                for (int u = 0; u < 2; ++u) acc[g][u] = (f32x4){0.f, 0.f, 0.f, 0.f};
            #pragma unroll
            for (int kt = 0; kt < 4; ++kt) {
                bf16x8 a = *(const bf16x8*)&Al[t & 1][fr_][kt * 32 + kb0];
                #pragma unroll
                for (int g = 0; g < 4; ++g)
                    #pragma unroll
                    for (int u = 0; u < 2; ++u) acc[g][u] = mfma16(a, bf[g][u][kt], acc[g][u]);
            }
            // combine hi (quads 0,1) + lo (quads 2,3): UNIFORM indices only
            #pragma unroll
            for (int g = 0; g < 4; ++g)
                #pragma unroll
                for (int u = 0; u < 2; ++u)
                    #pragma unroll
                    for (int rr = 0; rr < 4; ++rr)
                        acc[g][u][rr] += __shfl_xor(acc[g][u][rr], 32);
        }
        int tt = dir ? (255 - t) : t;
        #pragma unroll
        for (int rr = 0; rr < 4; ++rr) {
            int s = qrow * 4 + rr;
            float gg[4];
            #pragma unroll
            for (int g = 0; g < 4; ++g) {
                float pv = (t > 0) ? (uq ? acc[g][1][rr] : acc[g][0][rr]) : 0.f;
                gg[g] = xv[rr][g] + pv;
            }
            c[rr] = fsig(gg[1]) * c[rr] + fsig(gg[0]) * ftanh(gg[2]);
            float h = fsig(gg[3]) * ftanh(c[rr]);
            u16 hh = f2bf(h);
            Al[(t + 1) & 1][s][colw] = hh;
            Al[(t + 1) & 1][8 + s][colw] = f2bf(h - bf2f(hh));
            xout[((size_t)tt * 256 + b0 + s) * 256 + coloff + colw] = h;
            if (t == s1 - 1) hp[(size_t)(b0 + s) * K + colw] = h;
        }
        __syncthreads();
    }
    #pragma unroll
    for (int rr = 0; rr < 4; ++rr)
        cb[(size_t)(b0 + qrow * 4 + rr) * K + colw] = c[rr];
}

template<int OUTY>
DEV void recur2_body(char* lds, int bid,
    const float* __restrict__ xg, const float* __restrict__ whh,
    float* __restrict__ cb, u64* hb,
    float* __restrict__ xout, float* __restrict__ yout,
    const int* __restrict__ lastidx,
    const float* __restrict__ bng, const float* __restrict__ bnb,
    int s0, int s1)
{
    constexpr int K = 256, MB = 8, N4 = 1024;
    constexpr int CNT = MB * K / 256;   // 8 poll words per thread
    typedef u16 Al2Row[264];
    Al2Row* Al = (Al2Row*)lds;          // [16][264] = 8448 B

    int tid = threadIdx.x, lane = tid & 63, w = tid >> 6;
    int fr_ = lane & 15, quad = lane >> 4, kb0 = quad * 8;
    int group = bid >> 2, cw = bid & 3;
    u64* hbg = hb + (size_t)group * (2 * MB * K);
    int col = cw * 64 + w * 16 + fr_;

    bf16x8 bf[4][8];
    #pragma unroll
    for (int g = 0; g < 4; ++g) {
        const float* src = whh + (size_t)(g * 256 + col) * K;
        #pragma unroll
        for (int kt = 0; kt < 8; ++kt) {
            f32x4 a = *(const f32x4*)(src + kt * 32 + kb0);
            f32x4 b = *(const f32x4*)(src + kt * 32 + kb0 + 4);
            bf16x8 wv;
            #pragma unroll
            for (int i = 0; i < 8; ++i) wv[i] = (short)f2bf((i < 4) ? a[i] : b[i - 4]);
            bf[g][kt] = wv;
        }
    }

    int qrow = quad & 1, rhalf = quad >> 1;
    int sp[2], bs[2]; float c[2];
    #pragma unroll
    for (int j = 0; j < 2; ++j) {
        sp[j] = qrow * 4 + rhalf * 2 + j;
        bs[j] = group * 8 + sp[j];
        c[j] = (s0 > 0) ? cb[(size_t)bs[j] * K + col] : 0.f;
    }
    int lastb[2] = { -1, -1 };
    float bngv = 0.f, bnbv = 0.f;
    if (OUTY) {
        bool is64 = (lastidx[1] | lastidx[3] | lastidx[5] | lastidx[7] |
                     lastidx[9] | lastidx[11] | lastidx[13] | lastidx[15]) == 0;
        lastb[0] = is64 ? lastidx[2 * bs[0]] : lastidx[bs[0]];
        lastb[1] = is64 ? lastidx[2 * bs[1]] : lastidx[bs[1]];
        bngv = bng[col] * rsqrtf(1.0f + 1e-5f);
        bnbv = bnb[col];
    }

    for (int t = s0; t < s1; ++t) {
        int xrow = t - s0;
        float xv[2][4];
        #pragma unroll
        for (int j = 0; j < 2; ++j) {
            const float* xp = xg + ((size_t)(xrow * 256 + bs[j])) * N4 + col;
            #pragma unroll
            for (int g = 0; g < 4; ++g) xv[j][g] = xp[g * 256];
        }
        f32x4 acc[4];
        if (t > 0) {
            u64* hsrc = hbg + (size_t)(t & 1) * (MB * K);
            u64 v[CNT];
            #pragma unroll
            for (int i = 0; i < CNT; ++i)
                v[i] = __hip_atomic_load(hsrc + tid + i * 256,
                                         __ATOMIC_RELAXED, __HIP_MEMORY_SCOPE_AGENT);
            for (;;) {
                bool ok = true;
                #pragma unroll
                for (int i = 0; i < CNT; ++i)
                    if ((u32)(v[i] >> 32) != (u32)t) ok = false;
                if (ok) break;
                #pragma unroll
                for (int i = 0; i < CNT; ++i)
                    if ((u32)(v[i] >> 32) != (u32)t)
                        v[i] = __hip_atomic_load(hsrc + tid + i * 256,
                                                 __ATOMIC_RELAXED, __HIP_MEMORY_SCOPE_AGENT);
            }
            #pragma unroll
            for (int i = 0; i < CNT; ++i) {
                u32 d = (u32)v[i];
                Al[i][tid]     = (u16)(d & 0xffffu);
                Al[8 + i][tid] = (u16)(d >> 16);
            }
            __syncthreads();
            #pragma unroll
            for (int g = 0; g < 4; ++g) acc[g] = (f32x4){0.f, 0.f, 0.f, 0.f};
            #pragma unroll
            for (int kt = 0; kt < 8; ++kt) {
                bf16x8 a = *(const bf16x8*)&Al[fr_][kt * 32 + kb0];
                #pragma unroll
                for (int g = 0; g < 4; ++g) acc[g] = mfma16(a, bf[g][kt], acc[g]);
            }
            #pragma unroll
            for (int g = 0; g < 4; ++g)
                #pragma unroll
                for (int rr = 0; rr < 4; ++rr)
                    acc[g][rr] += __shfl_xor(acc[g][rr], 32);
        }
        #pragma unroll
        for (int j = 0; j < 2; ++j) {
            float gg[4];
            #pragma unroll
            for (int g = 0; g < 4; ++g) {
                float pv = (t > 0) ? (rhalf ? acc[g][2 + j] : acc[g][j]) : 0.f;
                gg[g] = xv[j][g] + pv;
            }
            c[j] = fsig(gg[1]) * c[j] + fsig(gg[0]) * ftanh(gg[2]);
            float h = fsig(gg[3]) * ftanh(c[j]);
            u16 hh = f2bf(h);
            u16 hl = f2bf(h - bf2f(hh));
            u64 word = (u64)((u32)hh | ((u32)hl << 16))
                     | ((u64)(u32)(t + 1) << 32);
            __hip_atomic_store(hbg + (size_t)((t + 1) & 1) * (MB * K) + (size_t)sp[j] * K + col,
                               word, __ATOMIC_RELAXED, __HIP_MEMORY_SCOPE_AGENT);
            if (OUTY == 0) {
                xout[((size_t)t * 256 + bs[j]) * 256 + col] = h;
            } else if (t == lastb[j]) {
                float y = h * bngv + bnbv;
                y = y > 0.f ? y : 0.f;
                yout[(size_t)bs[j] * 256 + col] = y;
            }
        }
        if (t + 1 < s1) __syncthreads();   // protect Al before next stage (poll also fences)
    }
    #pragma unroll
    for (int j = 0; j < 2; ++j) cb[(size_t)bs[j] * K + col] = c[j];
}

// ---------------------------------------------------------------------------
// Kernels
// ---------------------------------------------------------------------------
__global__ __launch_bounds__(256) void xg_fr_kernel(
    const float* embed, const float* Wf, const float* bf_,
    const float* Wr, const float* br_,
    float* xgf, float* xgr, int t0f, int t0r)
{
    __shared__ __align__(16) char lds[10240];
    xg_fr_body(lds, blockIdx.x, blockIdx.y, gridDim.y >> 1,
               embed, Wf, bf_, Wr, br_, xgf, xgr, t0f, t0r);
}

__global__ __launch_bounds__(256) void xg_l_kernel(
    const float* X, const float* W, const float* bias, float* out, int t0)
{
    __shared__ __align__(16) char lds[10240];
    xg_l_body(lds, blockIdx.x, blockIdx.y, X, W, bias, out, t0);
}

// fused: recur1 (wgs 0..63, dedicated CUs) + persistent xg_fr GEMM wgs
// (64..255) looping over the next chunk's 2048 tiles (8 x 2*CH*4).
__global__ __launch_bounds__(256) void fused1_kernel(
    const float* xgf, const float* xgr,
    const float* whhf, const float* whhr,
    float* cbf, float* cbr, float* hpf, float* hpr,
    float* xout, int s0, int s1, int haveNext,
    const float* embed, const float* Wf, const float* bf_,
    const float* Wr, const float* br_,
    float* nxgf, float* nxgr, int t0f, int t0r)
{
    __shared__ __align__(16) char lds[10240];
    int bid = blockIdx.x;
    if (bid < 64) {
        recur1_body(lds, bid, xgf, xgr, whhf, whhr, cbf, cbr, hpf, hpr, xout, s0, s1);
    } else if (haveNext) {
        for (int g = bid - 64; g < 8 * 2 * CH * 4; g += 192)
            xg_fr_body(lds, g & 7, g >> 3, CH * 4,
                       embed, Wf, bf_, Wr, br_, nxgf, nxgr, t0f, t0r);
    }
}

// fused: recur2 (wgs 0..127, dedicated CUs) + persistent xg_l GEMM wgs
// (128..255) looping over the next chunk's 2048 tiles (16 x CH*4).
template<int OUTY>
__global__ __launch_bounds__(256) void fused2_kernel(
    const float* xg, const float* whh, float* cb, u64* hb,
    float* xout, float* yout, const int* lastidx,
    const float* bng, const float* bnb, int s0, int s1, int haveNext,
    const float* X, const float* Wih, const float* bih, float* nxg, int t0n)
{
    __shared__ __align__(16) char lds[10240];
    int bid = blockIdx.x;
    if (bid < 128) {
        recur2_body<OUTY>(lds, bid, xg, whh, cb, hb, xout, yout,
                          lastidx, bng, bnb, s0, s1);
    } else if (haveNext) {
        for (int g = bid - 128; g < 16 * CH * 4; g += 128)
            xg_l_body(lds, g & 15, g >> 4, X, Wih, bih, nxg, t0n);
    }
}

// ---------------------------------------------------------------------------
// layernorm over 256 channels. (unchanged)
// ---------------------------------------------------------------------------
template<int RESID>
__global__ __launch_bounds__(256) void ln_kernel(
    float* __restrict__ X, const float* __restrict__ R,
    const float* __restrict__ gw, const float* __restrict__ bw)
{
    int row  = blockIdx.x * 4 + (threadIdx.x >> 6);
    int lane = threadIdx.x & 63;
    float* xr = X + (size_t)row * 256;
    f32x4 v = *(const f32x4*)(xr + lane * 4);
    if (RESID) {
        f32x4 u = *(const f32x4*)(R + (size_t)row * 256 + lane * 4);
        v += u;
    }
    float s = v[0] + v[1] + v[2] + v[3];
    #pragma unroll
    for (int mm = 1; mm < 64; mm <<= 1) s += __shfl_xor(s, mm, 64);
    float mu = s * (1.0f / 256.0f);
    f32x4 e = v - mu;
    float q = e[0]*e[0] + e[1]*e[1] + e[2]*e[2] + e[3]*e[3];
    #pragma unroll
    for (int mm = 1; mm < 64; mm <<= 1) q += __shfl_xor(q, mm, 64);
    float rs = rsqrtf(q * (1.0f / 256.0f) + 1e-5f);
    int c0 = lane * 4;
    f32x4 o;
    #pragma unroll
    for (int i = 0; i < 4; ++i) o[i] = e[i] * rs * gw[c0 + i] + bw[c0 + i];
    *(f32x4*)(xr + lane * 4) = o;
}

// ---------------------------------------------------------------------------
// Launch
// ---------------------------------------------------------------------------
extern "C" void kernel_launch(void* const* d_in, const int* in_sizes, int n_in,
                              void* d_out, int out_size, void* d_ws, size_t ws_size,
                              hipStream_t stream)
{
    (void)in_sizes; (void)n_in; (void)out_size; (void)ws_size;
    const float* embed = (const float*)d_in[0];
    const int* lastidx = (const int*)d_in[1];
    const float* Wih_f = (const float*)d_in[2];
    const float* Whh_f = (const float*)d_in[3];
    const float* b_f   = (const float*)d_in[4];
    const float* Wih_r = (const float*)d_in[5];
    const float* Whh_r = (const float*)d_in[6];
    const float* b_r   = (const float*)d_in[7];
    const float* ln1g  = (const float*)d_in[8];
    const float* ln1b  = (const float*)d_in[9];
    const float* W1ih  = (const float*)d_in[10];
    const float* W1hh  = (const float*)d_in[11];
    const float* b1    = (const float*)d_in[12];
    const float* ln2g  = (const float*)d_in[13];
    const float* ln2b  = (const float*)d_in[14];
    const float* W2ih  = (const float*)d_in[15];
    const float* W2hh  = (const float*)d_in[16];
    const float* b2    = (const float*)d_in[17];
    const float* bng   = (const float*)d_in[18];
    const float* bnb   = (const float*)d_in[19];

    const size_t MiB = 1024 * 1024;
    char* ws = (char*)d_ws;
    float* XGa = (float*)ws;                                // 32 MiB
    float* XGb = (float*)(ws + 32 * MiB);                   // 32 MiB
    float* XGaR = XGa + (size_t)CH * 256 * 512;             // rev half (stage 1)
    float* XGbR = XGb + (size_t)CH * 256 * 512;
    float* X1  = (float*)(ws + 64 * MiB);                   // 64 MiB
    float* X2  = (float*)(ws + 128 * MiB);                  // 64 MiB
    char*  p   = ws + 192 * MiB;
    u64* hb1 = (u64*)p;                         p += 1024 * 1024;
    u64* hb2 = (u64*)p;                         p += 1024 * 1024;
    float* cbf = (float*)p;                     p += 128 * 1024;
    float* cbr = (float*)p;                     p += 128 * 1024;
    float* cb1 = (float*)p;                     p += 256 * 1024;
    float* cb2 = (float*)p;                     p += 256 * 1024;
    float* hpf = (float*)p;                     p += 128 * 1024;
    float* hpr = (float*)p;                     // 128 KiB

    const int nch = 256 / CH;   // 8

    // stage 1: bidirectional H=128 LSTM -> X1 (raw concat)
    xg_fr_kernel<<<dim3(8, 2 * CH * 4), 256, 0, stream>>>(
        embed, Wih_f, b_f, Wih_r, b_r, XGa, XGaR, 0, 256 - CH);
    for (int i = 0; i < nch; ++i) {
        float* cxf = (i & 1) ? XGb  : XGa;
        float* cxr = (i & 1) ? XGbR : XGaR;
        float* nxf = (i & 1) ? XGa  : XGb;
        float* nxr = (i & 1) ? XGaR : XGbR;
        fused1_kernel<<<256, 256, 0, stream>>>(
            cxf, cxr, Whh_f, Whh_r, cbf, cbr, hpf, hpr,
            X1, CH * i, CH * (i + 1), (i < nch - 1) ? 1 : 0,
            embed, Wih_f, b_f, Wih_r, b_r, nxf, nxr,
            CH * (i + 1), 256 - CH * (i + 2));
    }
    ln_kernel<0><<<16384, 256, 0, stream>>>(X1, nullptr, ln1g, ln1b);

    // stage 2: H2 LSTM layer 1 -> X2 (raw)
    xg_l_kernel<<<dim3(16, CH * 4), 256, 0, stream>>>(X1, W1ih, b1, XGa, 0);
    for (int i = 0; i < nch; ++i) {
        float* cur = (i & 1) ? XGb : XGa;
        float* nxt = (i & 1) ? XGa : XGb;
        fused2_kernel<0><<<256, 256, 0, stream>>>(
            cur, W1hh, cb1, hb1,
            X2, nullptr, nullptr, nullptr, nullptr,
            CH * i, CH * (i + 1), (i < nch - 1) ? 1 : 0,
            X1, W1ih, b1, nxt, CH * (i + 1));
    }
    ln_kernel<1><<<16384, 256, 0, stream>>>(X2, X1, ln2g, ln2b);

    // stage 3: H2 LSTM layer 2 -> gathered y (fp32 out)
    xg_l_kernel<<<dim3(16, CH * 4), 256, 0, stream>>>(X2, W2ih, b2, XGa, 0);
    for (int i = 0; i < nch; ++i) {
        float* cur = (i & 1) ? XGb : XGa;
        float* nxt = (i & 1) ? XGa : XGb;
        fused2_kernel<1><<<256, 256, 0, stream>>>(
            cur, W2hh, cb2, hb2,
            nullptr, (float*)d_out, lastidx, bng, bnb,
            CH * i, CH * (i + 1), (i < nch - 1) ? 1 : 0,
            X2, W2ih, b2, nxt, CH * (i + 1));
    }
}

// Round 12
// 2572.434 us; speedup vs baseline: 1.2034x; 1.2034x over previous
//
#include <hip/hip_runtime.h>
#include <cstdint>
#include <cstddef>

typedef unsigned short u16;
typedef unsigned int u32;
typedef unsigned long long u64;
typedef __attribute__((ext_vector_type(8))) short bf16x8;  // 8 x bf16 (4 VGPRs)
typedef __attribute__((ext_vector_type(4))) float f32x4;

#define DEV __device__ __forceinline__

DEV float bf2f(u16 h) { union { u32 u; float f; } x; x.u = ((u32)h) << 16; return x.f; }
DEV u16 f2bf(float f) {
    union { float f; u32 u; } x; x.f = f;
    u32 u = x.u;
    return (u16)((u + 0x7fffu + ((u >> 16) & 1u)) >> 16);   // RNE
}
// fast gate math: __expf + v_rcp_f32; rel err ~1e-6 << bf16 weight rounding
DEV float fsig(float x)  { float e = __expf(-x);      return __builtin_amdgcn_rcpf(1.0f + e); }
DEV float ftanh(float x) { float e = __expf(2.0f * x); return 1.0f - 2.0f * __builtin_amdgcn_rcpf(e + 1.0f); }
DEV f32x4 mfma16(bf16x8 a, bf16x8 b, f32x4 c) {
    return __builtin_amdgcn_mfma_f32_16x16x32_bf16(a, b, c, 0, 0, 0);
}

// B=256, T=256, E=128, H=128 (per direction), H2=256. ALL tensors fp32.
// Sequential r9 structure (fusion attempts r10/r11 regressed: co-located
// GEMM work stretches the latency-bound recurrence 2.46 -> 4.4/5.2 us/step).
// GEMMs upgraded to 128x128 tiles (2x2 waves, 4x4 frags) for 2x MFMA:VALU.

// ---------------------------------------------------------------------------
// xg GEMM, first (bi) layer, fp32 in/out. 128x128 tile.
// out[tl*256+b, n] = bias[n] + sum_e embed[b,t0+tl,e]*Wih[n,e]
// A (embed) split hi/lo bf16 -> logical K=256 over E=128; W single bf16.
// grid = (4, 2*CHv*2): lower half fwd, upper half rev.
// ---------------------------------------------------------------------------
__global__ __launch_bounds__(256) void xg_fr_kernel(
    const float* __restrict__ embed,
    const float* __restrict__ Wf, const float* __restrict__ bf_,
    const float* __restrict__ Wr, const float* __restrict__ br_,
    float* __restrict__ xgf, float* __restrict__ xgr, int t0f, int t0r)
{
    __shared__ __align__(16) u16 As[128][40];
    __shared__ __align__(16) u16 Bs[128][40];
    int tid = threadIdx.x;
    int bx = blockIdx.x;              // 0..3  (N/128)
    int by = blockIdx.y;
    int half = gridDim.y >> 1;
    bool isR = by >= half;
    int m0 = (by - (isR ? half : 0)) * 128;
    const float* W    = isR ? Wr  : Wf;
    const float* bias = isR ? br_ : bf_;
    float* out        = isR ? xgr : xgf;
    int tbase         = isR ? t0r : t0f;
    int n0 = bx * 128;

    int r  = tid >> 1;                // 0..127 staging row
    int kc = (tid & 1) * 16;          // 0 or 16
    int m  = m0 + r;
    int tl = m >> 8, bb = m & 255;
    const float* arow = embed + ((size_t)(bb * 256 + (tbase + tl)) * 128);
    const float* brow = W + ((size_t)(n0 + r) * 128);

    f32x4 acc[4][4];
    #pragma unroll
    for (int i = 0; i < 4; ++i)
        #pragma unroll
        for (int j = 0; j < 4; ++j) acc[i][j] = (f32x4){0.f, 0.f, 0.f, 0.f};
    int lane = tid & 63, w = tid >> 6;
    int fr_ = lane & 15, kb0 = (lane >> 4) * 8;
    int wr = (w >> 1) * 64, wc = (w & 1) * 64;

    for (int kt = 0; kt < 8; ++kt) {
        int sc = (kt & 3) * 32 + kc;  // source col block
        bool lo = kt >= 4;
        f32x4 a0 = *(const f32x4*)(arow + sc);
        f32x4 a1 = *(const f32x4*)(arow + sc + 4);
        f32x4 a2 = *(const f32x4*)(arow + sc + 8);
        f32x4 a3 = *(const f32x4*)(arow + sc + 12);
        f32x4 b0 = *(const f32x4*)(brow + sc);
        f32x4 b1 = *(const f32x4*)(brow + sc + 4);
        f32x4 b2 = *(const f32x4*)(brow + sc + 8);
        f32x4 b3 = *(const f32x4*)(brow + sc + 12);
        bf16x8 hv0, hv1, wv0, wv1;
        #pragma unroll
        for (int i = 0; i < 8; ++i) {
            float va = (i < 4) ? a0[i] : a1[i - 4];
            float vb = (i < 4) ? a2[i] : a3[i - 4];
            u16 ha = f2bf(va), hb = f2bf(vb);
            hv0[i] = (short)(lo ? f2bf(va - bf2f(ha)) : ha);
            hv1[i] = (short)(lo ? f2bf(vb - bf2f(hb)) : hb);
            float wa = (i < 4) ? b0[i] : b1[i - 4];
            float wb = (i < 4) ? b2[i] : b3[i - 4];
            wv0[i] = (short)f2bf(wa);
            wv1[i] = (short)f2bf(wb);
        }
        *(bf16x8*)&As[r][kc] = hv0;  *(bf16x8*)&As[r][kc + 8] = hv1;
        *(bf16x8*)&Bs[r][kc] = wv0;  *(bf16x8*)&Bs[r][kc + 8] = wv1;
        __syncthreads();
        bf16x8 bfrg[4], afrg[4];
        #pragma unroll
        for (int nt = 0; nt < 4; ++nt) bfrg[nt] = *(const bf16x8*)&Bs[wc + nt * 16 + fr_][kb0];
        #pragma unroll
        for (int mt = 0; mt < 4; ++mt) afrg[mt] = *(const bf16x8*)&As[wr + mt * 16 + fr_][kb0];
        #pragma unroll
        for (int mt = 0; mt < 4; ++mt)
            #pragma unroll
            for (int nt = 0; nt < 4; ++nt)
                acc[mt][nt] = mfma16(afrg[mt], bfrg[nt], acc[mt][nt]);
        __syncthreads();
    }
    int rq = (lane >> 4) * 4;
    #pragma unroll
    for (int nt = 0; nt < 4; ++nt) {
        int col = n0 + wc + nt * 16 + fr_;
        float bvv = bias[col];
        #pragma unroll
        for (int mt = 0; mt < 4; ++mt)
            #pragma unroll
            for (int rr = 0; rr < 4; ++rr) {
                int mrow = m0 + wr + mt * 16 + rq + rr;
                out[(size_t)mrow * 512 + col] = acc[mt][nt][rr] + bvv;
            }
    }
}

// ---------------------------------------------------------------------------
// xg GEMM, H2 layers, fp32 in/out. 128x128 tile. X split hi/lo (logical
// K=512 over 256). grid = (8, CHv*2)
// ---------------------------------------------------------------------------
__global__ __launch_bounds__(256) void xg_l_kernel(
    const float* __restrict__ X, const float* __restrict__ W,
    const float* __restrict__ bias, float* __restrict__ out, int t0)
{
    __shared__ __align__(16) u16 As[128][40];
    __shared__ __align__(16) u16 Bs[128][40];
    int tid = threadIdx.x;
    int bx = blockIdx.x;              // 0..7
    int by = blockIdx.y;
    int m0 = by * 128, n0 = bx * 128;
    int r  = tid >> 1;                // 0..127
    int kc = (tid & 1) * 16;
    int m  = m0 + r;
    int tl = m >> 8, bb = m & 255;
    const float* arow = X + ((size_t)((t0 + tl) * 256 + bb) * 256);
    const float* brow = W + ((size_t)(n0 + r) * 256);

    f32x4 acc[4][4];
    #pragma unroll
    for (int i = 0; i < 4; ++i)
        #pragma unroll
        for (int j = 0; j < 4; ++j) acc[i][j] = (f32x4){0.f, 0.f, 0.f, 0.f};
    int lane = tid & 63, w = tid >> 6;
    int fr_ = lane & 15, kb0 = (lane >> 4) * 8;
    int wr = (w >> 1) * 64, wc = (w & 1) * 64;

    for (int kt = 0; kt < 16; ++kt) {
        int sc = (kt & 7) * 32 + kc;
        bool lo = kt >= 8;
        f32x4 a0 = *(const f32x4*)(arow + sc);
        f32x4 a1 = *(const f32x4*)(arow + sc + 4);
        f32x4 a2 = *(const f32x4*)(arow + sc + 8);
        f32x4 a3 = *(const f32x4*)(arow + sc + 12);
        f32x4 b0 = *(const f32x4*)(brow + sc);
        f32x4 b1 = *(const f32x4*)(brow + sc + 4);
        f32x4 b2 = *(const f32x4*)(brow + sc + 8);
        f32x4 b3 = *(const f32x4*)(brow + sc + 12);
        bf16x8 hv0, hv1, wv0, wv1;
        #pragma unroll
        for (int i = 0; i < 8; ++i) {
            float va = (i < 4) ? a0[i] : a1[i - 4];
            float vb = (i < 4) ? a2[i] : a3[i - 4];
            u16 ha = f2bf(va), hb = f2bf(vb);
            hv0[i] = (short)(lo ? f2bf(va - bf2f(ha)) : ha);
            hv1[i] = (short)(lo ? f2bf(vb - bf2f(hb)) : hb);
            float wa = (i < 4) ? b0[i] : b1[i - 4];
            float wb = (i < 4) ? b2[i] : b3[i - 4];
            wv0[i] = (short)f2bf(wa);
            wv1[i] = (short)f2bf(wb);
        }
        *(bf16x8*)&As[r][kc] = hv0;  *(bf16x8*)&As[r][kc + 8] = hv1;
        *(bf16x8*)&Bs[r][kc] = wv0;  *(bf16x8*)&Bs[r][kc + 8] = wv1;
        __syncthreads();
        bf16x8 bfrg[4], afrg[4];
        #pragma unroll
        for (int nt = 0; nt < 4; ++nt) bfrg[nt] = *(const bf16x8*)&Bs[wc + nt * 16 + fr_][kb0];
        #pragma unroll
        for (int mt = 0; mt < 4; ++mt) afrg[mt] = *(const bf16x8*)&As[wr + mt * 16 + fr_][kb0];
        #pragma unroll
        for (int mt = 0; mt < 4; ++mt)
            #pragma unroll
            for (int nt = 0; nt < 4; ++nt)
                acc[mt][nt] = mfma16(afrg[mt], bfrg[nt], acc[mt][nt]);
        __syncthreads();
    }
    int rq = (lane >> 4) * 4;
    #pragma unroll
    for (int nt = 0; nt < 4; ++nt) {
        int col = n0 + wc + nt * 16 + fr_;
        float bvv = bias[col];
        #pragma unroll
        for (int mt = 0; mt < 4; ++mt)
            #pragma unroll
            for (int rr = 0; rr < 4; ++rr) {
                int mrow = m0 + wr + mt * 16 + rq + rr;
                out[(size_t)mrow * 1024 + col] = acc[mt][nt][rr] + bvv;
            }
    }
}

// ---------------------------------------------------------------------------
// layernorm over 256 channels. (r9 verbatim)
// ---------------------------------------------------------------------------
template<int RESID>
__global__ __launch_bounds__(256) void ln_kernel(
    float* __restrict__ X, const float* __restrict__ R,
    const float* __restrict__ gw, const float* __restrict__ bw)
{
    int row  = blockIdx.x * 4 + (threadIdx.x >> 6);
    int lane = threadIdx.x & 63;
    float* xr = X + (size_t)row * 256;
    f32x4 v = *(const f32x4*)(xr + lane * 4);
    if (RESID) {
        f32x4 u = *(const f32x4*)(R + (size_t)row * 256 + lane * 4);
        v += u;
    }
    float s = v[0] + v[1] + v[2] + v[3];
    #pragma unroll
    for (int mm = 1; mm < 64; mm <<= 1) s += __shfl_xor(s, mm, 64);
    float mu = s * (1.0f / 256.0f);
    f32x4 e = v - mu;
    float q = e[0]*e[0] + e[1]*e[1] + e[2]*e[2] + e[3]*e[3];
    #pragma unroll
    for (int mm = 1; mm < 64; mm <<= 1) q += __shfl_xor(q, mm, 64);
    float rs = rsqrtf(q * (1.0f / 256.0f) + 1e-5f);
    int c0 = lane * 4;
    f32x4 o;
    #pragma unroll
    for (int i = 0; i < 4; ++i) o[i] = e[i] * rs * gw[c0 + i] + bw[c0 + i];
    *(f32x4*)(xr + lane * 4) = o;
}

// ---------------------------------------------------------------------------
// Stage-1 recurrence (H=128). (r9 verbatim — C-domain gate fusion, one
// barrier/step, uniform-operand shfl hi/lo combine, Whh in VGPRs)
// ---------------------------------------------------------------------------
__global__ __launch_bounds__(256) void recur1_kernel(
    const float* __restrict__ xgf, const float* __restrict__ xgr,
    const float* __restrict__ whhf, const float* __restrict__ whhr,
    float* __restrict__ cbf, float* __restrict__ cbr,
    float* __restrict__ hpf, float* __restrict__ hpr,
    float* __restrict__ xout, int s0, int s1)
{
    constexpr int K = 128, N4 = 512;
    __shared__ __align__(16) u16 Al[2][16][K + 8];

    int tid = threadIdx.x, lane = tid & 63, w = tid >> 6;
    int fr_ = lane & 15, quad = lane >> 4, kb0 = quad * 8;
    int bid = blockIdx.x;
    int dir = bid >> 5, gidx = bid & 31;
    const float* xg  = dir ? xgr  : xgf;
    const float* whh = dir ? whhr : whhf;
    float* cb = dir ? cbr : cbf;
    float* hp = dir ? hpr : hpf;
    int coloff = dir ? 128 : 0;

    bf16x8 bf[4][2][4];
    #pragma unroll
    for (int g = 0; g < 4; ++g)
        #pragma unroll
        for (int u = 0; u < 2; ++u) {
            const float* src = whh + (size_t)(g * K + w * 32 + u * 16 + fr_) * K;
            #pragma unroll
            for (int kt = 0; kt < 4; ++kt) {
                f32x4 a = *(const f32x4*)(src + kt * 32 + kb0);
                f32x4 b = *(const f32x4*)(src + kt * 32 + kb0 + 4);
                bf16x8 wv;
                #pragma unroll
                for (int i = 0; i < 8; ++i) wv[i] = (short)f2bf((i < 4) ? a[i] : b[i - 4]);
                bf[g][u][kt] = wv;
            }
        }

    int uq = quad >> 1, qrow = quad & 1;
    int colw = w * 32 + uq * 16 + fr_;        // 0..127
    int b0 = gidx * 8;
    float c[4];
    #pragma unroll
    for (int rr = 0; rr < 4; ++rr)
        c[rr] = (s0 > 0) ? cb[(size_t)(b0 + qrow * 4 + rr) * K + colw] : 0.f;

    if (s0 > 0) {
        for (int idx = tid; idx < 8 * K; idx += 256) {
            int sa = idx >> 7, k = idx & 127;
            float v = hp[(size_t)(b0 + sa) * K + k];
            u16 hh = f2bf(v);
            Al[s0 & 1][sa][k] = hh;
            Al[s0 & 1][8 + sa][k] = f2bf(v - bf2f(hh));
        }
    }
    __syncthreads();

    for (int t = s0; t < s1; ++t) {
        int xrow = dir ? (s1 - 1 - t) : (t - s0);
        float xv[4][4];
        #pragma unroll
        for (int rr = 0; rr < 4; ++rr) {
            const float* xp = xg + ((size_t)(xrow * 256 + b0 + qrow * 4 + rr)) * N4 + colw;
            #pragma unroll
            for (int g = 0; g < 4; ++g) xv[rr][g] = xp[g * K];
        }
        f32x4 acc[4][2];
        if (t > 0) {
            #pragma unroll
            for (int g = 0; g < 4; ++g)
                #pragma unroll
                for (int u = 0; u < 2; ++u) acc[g][u] = (f32x4){0.f, 0.f, 0.f, 0.f};
            #pragma unroll
            for (int kt = 0; kt < 4; ++kt) {
                bf16x8 a = *(const bf16x8*)&Al[t & 1][fr_][kt * 32 + kb0];
                #pragma unroll
                for (int g = 0; g < 4; ++g)
                    #pragma unroll
                    for (int u = 0; u < 2; ++u) acc[g][u] = mfma16(a, bf[g][u][kt], acc[g][u]);
            }
            #pragma unroll
            for (int g = 0; g < 4; ++g)
                #pragma unroll
                for (int u = 0; u < 2; ++u)
                    #pragma unroll
                    for (int rr = 0; rr < 4; ++rr)
                        acc[g][u][rr] += __shfl_xor(acc[g][u][rr], 32);
        }
        int tt = dir ? (255 - t) : t;
        #pragma unroll
        for (int rr = 0; rr < 4; ++rr) {
            int s = qrow * 4 + rr;
            float gg[4];
            #pragma unroll
            for (int g = 0; g < 4; ++g) {
                float pv = (t > 0) ? (uq ? acc[g][1][rr] : acc[g][0][rr]) : 0.f;
                gg[g] = xv[rr][g] + pv;
            }
            c[rr] = fsig(gg[1]) * c[rr] + fsig(gg[0]) * ftanh(gg[2]);
            float h = fsig(gg[3]) * ftanh(c[rr]);
            u16 hh = f2bf(h);
            Al[(t + 1) & 1][s][colw] = hh;
            Al[(t + 1) & 1][8 + s][colw] = f2bf(h - bf2f(hh));
            xout[((size_t)tt * 256 + b0 + s) * 256 + coloff + colw] = h;
            if (t == s1 - 1) hp[(size_t)(b0 + s) * K + colw] = h;
        }
        __syncthreads();
    }
    #pragma unroll
    for (int rr = 0; rr < 4; ++rr)
        cb[(size_t)(b0 + qrow * 4 + rr) * K + colw] = c[rr];
}

// ---------------------------------------------------------------------------
// H2 recurrence (K=256). (r9 verbatim — GROUP=4, tagged 64-bit agent-atomic
// h exchange, C-domain gate fusion, uniform-operand shfl combine, hot spin)
// ---------------------------------------------------------------------------
template<int OUTY>
__global__ __launch_bounds__(256) void recur2_kernel(
    const float* __restrict__ xg, const float* __restrict__ whh,
    float* __restrict__ cb, u64* hb,
    float* __restrict__ xout, float* __restrict__ yout,
    const int* __restrict__ lastidx,
    const float* __restrict__ bng, const float* __restrict__ bnb,
    int s0, int s1)
{
    constexpr int K = 256, MB = 8, N4 = 1024;
    constexpr int CNT = MB * K / 256;   // 8 poll words per thread
    __shared__ __align__(16) u16 Al[16][K + 8];

    int tid = threadIdx.x, lane = tid & 63, w = tid >> 6;
    int fr_ = lane & 15, quad = lane >> 4, kb0 = quad * 8;
    int bid = blockIdx.x;
    int group = bid >> 2, cw = bid & 3;
    u64* hbg = hb + (size_t)group * (2 * MB * K);
    int col = cw * 64 + w * 16 + fr_;         // 0..255

    bf16x8 bf[4][8];
    #pragma unroll
    for (int g = 0; g < 4; ++g) {
        const float* src = whh + (size_t)(g * 256 + col) * K;
        #pragma unroll
        for (int kt = 0; kt < 8; ++kt) {
            f32x4 a = *(const f32x4*)(src + kt * 32 + kb0);
            f32x4 b = *(const f32x4*)(src + kt * 32 + kb0 + 4);
            bf16x8 wv;
            #pragma unroll
            for (int i = 0; i < 8; ++i) wv[i] = (short)f2bf((i < 4) ? a[i] : b[i - 4]);
            bf[g][kt] = wv;
        }
    }

    int qrow = quad & 1, rhalf = quad >> 1;
    int sp[2], bs[2]; float c[2];
    #pragma unroll
    for (int j = 0; j < 2; ++j) {
        sp[j] = qrow * 4 + rhalf * 2 + j;
        bs[j] = group * 8 + sp[j];
        c[j] = (s0 > 0) ? cb[(size_t)bs[j] * K + col] : 0.f;
    }
    int lastb[2] = { -1, -1 };
    float bngv = 0.f, bnbv = 0.f;
    if (OUTY) {
        bool is64 = (lastidx[1] | lastidx[3] | lastidx[5] | lastidx[7] |
                     lastidx[9] | lastidx[11] | lastidx[13] | lastidx[15]) == 0;
        lastb[0] = is64 ? lastidx[2 * bs[0]] : lastidx[bs[0]];
        lastb[1] = is64 ? lastidx[2 * bs[1]] : lastidx[bs[1]];
        bngv = bng[col] * rsqrtf(1.0f + 1e-5f);
        bnbv = bnb[col];
    }

    for (int t = s0; t < s1; ++t) {
        int xrow = t - s0;
        float xv[2][4];
        #pragma unroll
        for (int j = 0; j < 2; ++j) {
            const float* xp = xg + ((size_t)(xrow * 256 + bs[j])) * N4 + col;
            #pragma unroll
            for (int g = 0; g < 4; ++g) xv[j][g] = xp[g * 256];
        }
        f32x4 acc[4];
        if (t > 0) {
            u64* hsrc = hbg + (size_t)(t & 1) * (MB * K);
            u64 v[CNT];
            #pragma unroll
            for (int i = 0; i < CNT; ++i)
                v[i] = __hip_atomic_load(hsrc + tid + i * 256,
                                         __ATOMIC_RELAXED, __HIP_MEMORY_SCOPE_AGENT);
            for (;;) {
                bool ok = true;
                #pragma unroll
                for (int i = 0; i < CNT; ++i)
                    if ((u32)(v[i] >> 32) != (u32)t) ok = false;
                if (ok) break;
                #pragma unroll
                for (int i = 0; i < CNT; ++i)
                    if ((u32)(v[i] >> 32) != (u32)t)
                        v[i] = __hip_atomic_load(hsrc + tid + i * 256,
                                                 __ATOMIC_RELAXED, __HIP_MEMORY_SCOPE_AGENT);
            }
            #pragma unroll
            for (int i = 0; i < CNT; ++i) {
                u32 d = (u32)v[i];
                Al[i][tid]     = (u16)(d & 0xffffu);
                Al[8 + i][tid] = (u16)(d >> 16);
            }
            __syncthreads();
            #pragma unroll
            for (int g = 0; g < 4; ++g) acc[g] = (f32x4){0.f, 0.f, 0.f, 0.f};
            #pragma unroll
            for (int kt = 0; kt < 8; ++kt) {
                bf16x8 a = *(const bf16x8*)&Al[fr_][kt * 32 + kb0];
                #pragma unroll
                for (int g = 0; g < 4; ++g) acc[g] = mfma16(a, bf[g][kt], acc[g]);
            }
            #pragma unroll
            for (int g = 0; g < 4; ++g)
                #pragma unroll
                for (int rr = 0; rr < 4; ++rr)
                    acc[g][rr] += __shfl_xor(acc[g][rr], 32);
        }
        #pragma unroll
        for (int j = 0; j < 2; ++j) {
            float gg[4];
            #pragma unroll
            for (int g = 0; g < 4; ++g) {
                float pv = (t > 0) ? (rhalf ? acc[g][2 + j] : acc[g][j]) : 0.f;
                gg[g] = xv[j][g] + pv;
            }
            c[j] = fsig(gg[1]) * c[j] + fsig(gg[0]) * ftanh(gg[2]);
            float h = fsig(gg[3]) * ftanh(c[j]);
            u16 hh = f2bf(h);
            u16 hl = f2bf(h - bf2f(hh));
            u64 word = (u64)((u32)hh | ((u32)hl << 16))
                     | ((u64)(u32)(t + 1) << 32);
            __hip_atomic_store(hbg + (size_t)((t + 1) & 1) * (MB * K) + (size_t)sp[j] * K + col,
                               word, __ATOMIC_RELAXED, __HIP_MEMORY_SCOPE_AGENT);
            if (OUTY == 0) {
                xout[((size_t)t * 256 + bs[j]) * 256 + col] = h;
            } else if (t == lastb[j]) {
                float y = h * bngv + bnbv;
                y = y > 0.f ? y : 0.f;
                yout[(size_t)bs[j] * 256 + col] = y;
            }
        }
        if (t + 1 < s1) __syncthreads();
    }
    #pragma unroll
    for (int j = 0; j < 2; ++j) cb[(size_t)bs[j] * K + col] = c[j];
}

// ---------------------------------------------------------------------------
// Launch (r9 structure; GEMM grids updated for 128x128 tiles)
// ---------------------------------------------------------------------------
extern "C" void kernel_launch(void* const* d_in, const int* in_sizes, int n_in,
                              void* d_out, int out_size, void* d_ws, size_t ws_size,
                              hipStream_t stream)
{
    (void)in_sizes; (void)n_in; (void)out_size;
    const float* embed = (const float*)d_in[0];
    const int* lastidx = (const int*)d_in[1];
    const float* Wih_f = (const float*)d_in[2];
    const float* Whh_f = (const float*)d_in[3];
    const float* b_f   = (const float*)d_in[4];
    const float* Wih_r = (const float*)d_in[5];
    const float* Whh_r = (const float*)d_in[6];
    const float* b_r   = (const float*)d_in[7];
    const float* ln1g  = (const float*)d_in[8];
    const float* ln1b  = (const float*)d_in[9];
    const float* W1ih  = (const float*)d_in[10];
    const float* W1hh  = (const float*)d_in[11];
    const float* b1    = (const float*)d_in[12];
    const float* ln2g  = (const float*)d_in[13];
    const float* ln2b  = (const float*)d_in[14];
    const float* W2ih  = (const float*)d_in[15];
    const float* W2hh  = (const float*)d_in[16];
    const float* b2    = (const float*)d_in[17];
    const float* bng   = (const float*)d_in[18];
    const float* bnb   = (const float*)d_in[19];

    const size_t MiB = 1024 * 1024;
    const int  CHv = (ws_size >= 196 * MiB) ? 64 : 32;
    const int  nch = 256 / CHv;
    char* ws = (char*)d_ws;
    const size_t xgBytes = (size_t)CHv * 256 * 1024 * 4;

    float* XG  = (float*)ws;
    float* XGr = XG + (size_t)CHv * 256 * 512;             // stage-1 rev half
    float* X1  = (float*)(ws + xgBytes);                   // 64 MiB
    float* X2  = (float*)(ws + xgBytes + 64 * MiB);        // 64 MiB
    char*  p   = ws + xgBytes + 128 * MiB;
    u64* hb1 = (u64*)p;                         p += 1024 * 1024;
    u64* hb2 = (u64*)p;                         p += 1024 * 1024;
    float* cbf = (float*)p;                     p += 128 * 1024;
    float* cbr = (float*)p;                     p += 128 * 1024;
    float* cb1 = (float*)p;                     p += 256 * 1024;
    float* cb2 = (float*)p;                     p += 256 * 1024;
    float* hpf = (float*)p;                     p += 128 * 1024;
    float* hpr = (float*)p;                     // 128 KiB

    // stage 1: bidirectional H=128 LSTM -> X1 (raw concat)
    for (int i = 0; i < nch; ++i) {
        xg_fr_kernel<<<dim3(4, 2 * CHv * 2), 256, 0, stream>>>(
            embed, Wih_f, b_f, Wih_r, b_r, XG, XGr, CHv * i, 256 - CHv * (i + 1));
        recur1_kernel<<<64, 256, 0, stream>>>(
            XG, XGr, Whh_f, Whh_r, cbf, cbr, hpf, hpr,
            X1, CHv * i, CHv * (i + 1));
    }
    ln_kernel<0><<<16384, 256, 0, stream>>>(X1, nullptr, ln1g, ln1b);

    // stage 2: H2 LSTM layer 1 -> X2 (raw)
    for (int i = 0; i < nch; ++i) {
        xg_l_kernel<<<dim3(8, CHv * 2), 256, 0, stream>>>(X1, W1ih, b1, XG, CHv * i);
        recur2_kernel<0><<<128, 256, 0, stream>>>(
            XG, W1hh, cb1, hb1,
            X2, nullptr, nullptr, nullptr, nullptr, CHv * i, CHv * (i + 1));
    }
    ln_kernel<1><<<16384, 256, 0, stream>>>(X2, X1, ln2g, ln2b);

    // stage 3: H2 LSTM layer 2 -> gathered y (fp32 out)
    for (int i = 0; i < nch; ++i) {
        xg_l_kernel<<<dim3(8, CHv * 2), 256, 0, stream>>>(X2, W2ih, b2, XG, CHv * i);
        recur2_kernel<1><<<128, 256, 0, stream>>>(
            XG, W2hh, cb2, hb2,
            nullptr, (float*)d_out, lastidx, bng, bnb, CHv * i, CHv * (i + 1));
    }
}